// Round 2
// baseline (463.442 us; speedup 1.0000x reference)
//
#include <hip/hip_runtime.h>
#include <hip/hip_bf16.h>

typedef __bf16 bf16;
typedef __bf16 bf16x8 __attribute__((ext_vector_type(8)));
typedef float  f32x4  __attribute__((ext_vector_type(4)));
typedef float  f32x8  __attribute__((ext_vector_type(8)));

#define MFMA16(A,B,C) __builtin_amdgcn_mfma_f32_16x16x32_bf16((A),(B),(C),0,0,0)

constexpr int   N_TOK = 49;
constexpr int   DIM_C = 256;
constexpr float SCALE = 0.17677669529663687f;   // 32^-0.5

// LDS layout (bf16 element offsets)
constexpr int QK_STRIDE  = 512;                       // qk rows: cols 0-255 Q(scaled), 256-511 K
constexpr int P_BASE     = 49 * 512;                  // 25088
constexpr int P_WSTRIDE  = 49 * 64;                   // 3136 per wave
constexpr int XB_BASE    = P_BASE;                    // x-tile overlay (stage-1 only; P dead then)
constexpr int VT_BASE    = P_BASE + 8 * P_WSTRIDE;    // 50176
constexpr int SMEM_ELEMS = VT_BASE + 256 * 64;        // 66560 elems = 133,120 B

// ws layout (bytes)
constexpr size_t CB_BYTES   = 64ull * 8 * 64 * 64 * 4;   // 8,388,608
constexpr int    QKVW_ELEMS = 768 * 256;                  // 196,608
constexpr int    PROJW_ELEMS= 256 * 256;                  // 65,536

__global__ __launch_bounds__(256) void build_cb_kernel(
    const float* __restrict__ bias_table, const float* __restrict__ mask,
    const int* __restrict__ rel_index, float* __restrict__ cb) {
  int idx = blockIdx.x * 256 + threadIdx.x;          // [64][8][64][64]
  int j = idx & 63, m = (idx >> 6) & 63, h = (idx >> 12) & 7, w = idx >> 15;
  float v = 0.f;
  if (j < N_TOK && m < N_TOK)
    v = bias_table[rel_index[m * 49 + j] * 8 + h] + mask[(w * 49 + m) * 49 + j];
  cb[idx] = v;
}

__global__ __launch_bounds__(256) void cvt_w_kernel(
    const float* __restrict__ qkv_w, const float* __restrict__ proj_w,
    bf16* __restrict__ qkv_wb, bf16* __restrict__ proj_wb) {
  int i = blockIdx.x * 256 + threadIdx.x;            // 262,144 total
  if (i < QKVW_ELEMS) qkv_wb[i] = (bf16)qkv_w[i];
  else                proj_wb[i - QKVW_ELEMS] = (bf16)proj_w[i - QKVW_ELEMS];
}

__global__ __launch_bounds__(512) void win_attn_kernel(
    const float* __restrict__ x, const bf16* __restrict__ qkv_wb,
    const float* __restrict__ qkv_b, const bf16* __restrict__ proj_wb,
    const float* __restrict__ proj_b, const float* __restrict__ cb,
    float* __restrict__ out) {
  __shared__ bf16 smem[SMEM_ELEMS];

  const int beta  = blockIdx.x;
  const int w_idx = beta >> 6;          // window id: 64 consecutive blocks share mask slice
  const int img   = beta & 63;
  const int b     = img * 64 + w_idx;   // flat batch: b % 64 == w_idx
  const int tid   = threadIdx.x;
  const int wv    = tid >> 6;           // wave = head
  const int l     = tid & 63;
  const int l15   = l & 15, lgp = l >> 4;

  const f32x4 fzero = {0.f, 0.f, 0.f, 0.f};
  const bf16x8 bzero = {(bf16)0.f,(bf16)0.f,(bf16)0.f,(bf16)0.f,
                        (bf16)0.f,(bf16)0.f,(bf16)0.f,(bf16)0.f};

  // zero vT pad columns j in [49,64)
  for (int i = tid; i < 256 * 15; i += 512) {
    int d = i / 15, j = 49 + i % 15;
    smem[VT_BASE + d * 64 + (j ^ ((d & 7) << 3))] = (bf16)0.f;
  }

  // ---------------- stage 0: x tile f32 -> LDS bf16 (overlay on P region) ---
  const float* xg = x + (size_t)b * (N_TOK * DIM_C);
  for (int c = tid; c < (N_TOK * DIM_C / 8); c += 512) {   // 1568 chunks of 8
    int m = c >> 5, k0 = (c & 31) * 8;
    f32x8 f = *reinterpret_cast<const f32x8*>(xg + m * 256 + k0);
    bf16x8 v;
#pragma unroll
    for (int e = 0; e < 8; ++e) v[e] = (bf16)f[e];
    *reinterpret_cast<bf16x8*>(&smem[XB_BASE + m * 256 + (k0 ^ ((m & 7) << 3))]) = v;
  }
  __syncthreads();

  // ---------------- stage 1: QKV = x @ qkv_w^T + qkv_b ----------------
  for (int ntg = 0; ntg < 2; ++ntg) {
    f32x4 acc[3][4];
    for (int t = 0; t < 3; ++t)
      for (int mt = 0; mt < 4; ++mt) acc[t][mt] = fzero;
    for (int k0 = 0; k0 < 8; ++k0) {
      const int kk = k0 * 32 + lgp * 8;
      bf16x8 A[4];
#pragma unroll
      for (int mt = 0; mt < 4; ++mt) {
        int m = mt * 16 + l15;
        A[mt] = (m < N_TOK)
            ? *reinterpret_cast<const bf16x8*>(
                  &smem[XB_BASE + m * 256 + (kk ^ ((m & 7) << 3))])
            : bzero;
      }
#pragma unroll
      for (int t = 0; t < 3; ++t) {
        int n = (wv * 6 + ntg * 3 + t) * 16 + l15;
        bf16x8 B = *reinterpret_cast<const bf16x8*>(qkv_wb + n * DIM_C + kk);
#pragma unroll
        for (int mt = 0; mt < 4; ++mt) acc[t][mt] = MFMA16(A[mt], B, acc[t][mt]);
      }
    }
#pragma unroll
    for (int t = 0; t < 3; ++t) {
      int c = (wv * 6 + ntg * 3 + t) * 16 + l15;
      float qb = qkv_b[c];
#pragma unroll
      for (int mt = 0; mt < 4; ++mt) {
#pragma unroll
        for (int r = 0; r < 4; ++r) {
          int m = mt * 16 + lgp * 4 + r;
          if (m < N_TOK) {
            float v = acc[t][mt][r] + qb;
            if (c < 512) {
              float vs = (c < 256) ? v * SCALE : v;           // pre-scale Q
              smem[m * QK_STRIDE + (c ^ ((m & 7) << 3))] = (bf16)vs;
            } else {
              int d = c - 512;                                // V transposed
              smem[VT_BASE + d * 64 + (m ^ ((d & 7) << 3))] = (bf16)v;
            }
          }
        }
      }
    }
  }
  __syncthreads();   // x-tile overlay dead from here; P region live

  // ---------------- stage 2 (per wave = per head): S, softmax, PV ----------
  const int h = wv;
  bf16* pbuf = smem + P_BASE + wv * P_WSTRIDE;

  f32x4 s[4][4];
  {
    bf16x8 A[4], B[4];
#pragma unroll
    for (int mt = 0; mt < 4; ++mt) {
      int m = mt * 16 + l15;
      A[mt] = *reinterpret_cast<const bf16x8*>(
          &smem[m * QK_STRIDE + ((h * 32 + lgp * 8) ^ ((m & 7) << 3))]);
    }
#pragma unroll
    for (int jt = 0; jt < 4; ++jt) {
      int n = jt * 16 + l15;
      B[jt] = *reinterpret_cast<const bf16x8*>(
          &smem[n * QK_STRIDE + ((256 + h * 32 + lgp * 8) ^ ((n & 7) << 3))]);
    }
#pragma unroll
    for (int mt = 0; mt < 4; ++mt)
#pragma unroll
      for (int jt = 0; jt < 4; ++jt) s[mt][jt] = MFMA16(A[mt], B[jt], fzero);
  }

  const float* cbp = cb + ((size_t)(w_idx * 8 + h)) * 64 * 64;
  float rinv[4][4];
#pragma unroll
  for (int mt = 0; mt < 4; ++mt) {
    float lgt[4][4];                           // [jt][r]
#pragma unroll
    for (int jt = 0; jt < 4; ++jt) {
      int jc = jt * 16 + l15;
#pragma unroll
      for (int r = 0; r < 4; ++r) {
        int m = mt * 16 + lgp * 4 + r;
        float v = s[mt][jt][r] + cbp[m * 64 + jc];
        if (jc >= N_TOK) v = -3.0e38f;         // kill pad keys (incl. NaN garbage)
        lgt[jt][r] = v;
      }
    }
#pragma unroll
    for (int r = 0; r < 4; ++r) {
      float mx = fmaxf(fmaxf(lgt[0][r], lgt[1][r]), fmaxf(lgt[2][r], lgt[3][r]));
      mx = fmaxf(mx, __shfl_xor(mx, 1));
      mx = fmaxf(mx, __shfl_xor(mx, 2));
      mx = fmaxf(mx, __shfl_xor(mx, 4));
      mx = fmaxf(mx, __shfl_xor(mx, 8));
      float sum = 0.f;
#pragma unroll
      for (int jt = 0; jt < 4; ++jt) {
        float e = __expf(lgt[jt][r] - mx);
        lgt[jt][r] = e;
        sum += e;
      }
      sum += __shfl_xor(sum, 1);
      sum += __shfl_xor(sum, 2);
      sum += __shfl_xor(sum, 4);
      sum += __shfl_xor(sum, 8);
      rinv[mt][r] = 1.0f / sum;
      int m = mt * 16 + lgp * 4 + r;
      if (m < N_TOK) {
#pragma unroll
        for (int jt = 0; jt < 4; ++jt) {
          int j = jt * 16 + l15;
          pbuf[m * 64 + (j ^ ((m & 7) << 3))] = (bf16)lgt[jt][r];   // unnormalized
        }
      }
    }
  }

  // PV, normalize at store; ao reuses dead Q columns [h*32, h*32+32) of qk
#pragma unroll
  for (int mt = 0; mt < 4; ++mt) {
#pragma unroll
    for (int dt = 0; dt < 2; ++dt) {
      f32x4 acc = fzero;
#pragma unroll
      for (int ks = 0; ks < 2; ++ks) {
        int m = mt * 16 + l15;
        bf16x8 A = *reinterpret_cast<const bf16x8*>(
            &pbuf[m * 64 + ((ks * 32 + lgp * 8) ^ ((m & 7) << 3))]);
        int d = h * 32 + dt * 16 + l15;
        bf16x8 B = *reinterpret_cast<const bf16x8*>(
            &smem[VT_BASE + d * 64 + ((ks * 32 + lgp * 8) ^ ((d & 7) << 3))]);
        acc = MFMA16(A, B, acc);
      }
#pragma unroll
      for (int r = 0; r < 4; ++r) {
        int m = mt * 16 + lgp * 4 + r;
        if (m < N_TOK) {
          int c = h * 32 + dt * 16 + l15;
          smem[m * QK_STRIDE + (c ^ ((m & 7) << 3))] = (bf16)(acc[r] * rinv[mt][r]);
        }
      }
    }
  }
  __syncthreads();

  // ---------------- stage 3: out = ao @ proj_w^T + proj_b ----------------
  f32x4 acc2[2][4];
  for (int ci = 0; ci < 2; ++ci)
    for (int mt = 0; mt < 4; ++mt) acc2[ci][mt] = fzero;
  for (int k0 = 0; k0 < 8; ++k0) {
    int kk = k0 * 32 + lgp * 8;
    bf16x8 A[4];
#pragma unroll
    for (int mt = 0; mt < 4; ++mt) {
      int m = mt * 16 + l15;
      A[mt] = *reinterpret_cast<const bf16x8*>(
          &smem[m * QK_STRIDE + (kk ^ ((m & 7) << 3))]);
    }
#pragma unroll
    for (int ci = 0; ci < 2; ++ci) {
      int n = (wv * 2 + ci) * 16 + l15;
      bf16x8 B = *reinterpret_cast<const bf16x8*>(proj_wb + n * DIM_C + kk);
#pragma unroll
      for (int mt = 0; mt < 4; ++mt) acc2[ci][mt] = MFMA16(A[mt], B, acc2[ci][mt]);
    }
  }
  float* ob = out + (size_t)b * (N_TOK * DIM_C);
#pragma unroll
  for (int ci = 0; ci < 2; ++ci) {
    int c = (wv * 2 + ci) * 16 + l15;
    float pb = proj_b[c];
#pragma unroll
    for (int mt = 0; mt < 4; ++mt) {
#pragma unroll
      for (int r = 0; r < 4; ++r) {
        int m = mt * 16 + lgp * 4 + r;
        if (m < N_TOK) ob[m * DIM_C + c] = acc2[ci][mt][r] + pb;
      }
    }
  }
}

extern "C" void kernel_launch(void* const* d_in, const int* in_sizes, int n_in,
                              void* d_out, int out_size, void* d_ws, size_t ws_size,
                              hipStream_t stream) {
  const float* x          = (const float*)d_in[0];
  const float* mask       = (const float*)d_in[1];
  const float* qkv_w      = (const float*)d_in[2];
  const float* qkv_b      = (const float*)d_in[3];
  const float* proj_w     = (const float*)d_in[4];
  const float* proj_b     = (const float*)d_in[5];
  const float* bias_table = (const float*)d_in[6];
  const int*   rel_index  = (const int*)d_in[7];

  float* cb      = (float*)d_ws;                                   // 8 MB
  bf16*  qkv_wb  = (bf16*)((char*)d_ws + CB_BYTES);                // 384 KB
  bf16*  proj_wb = (bf16*)((char*)d_ws + CB_BYTES + QKVW_ELEMS*2); // 128 KB

  hipLaunchKernelGGL(build_cb_kernel, dim3(8192), dim3(256), 0, stream,
                     bias_table, mask, rel_index, cb);
  hipLaunchKernelGGL(cvt_w_kernel, dim3(1024), dim3(256), 0, stream,
                     qkv_w, proj_w, qkv_wb, proj_wb);
  hipLaunchKernelGGL(win_attn_kernel, dim3(4096), dim3(512), 0, stream,
                     x, qkv_wb, qkv_b, proj_wb, proj_b, cb, (float*)d_out);
}